// Round 10
// baseline (798.377 us; speedup 1.0000x reference)
//
#include <hip/hip_runtime.h>

// GMAN pipeline, fully fused, MFMA edition. support = I -> per-block token GEMMs.
// B=64, P=Q=12, N=1024, D=64. Output [B,Q,N] fp32.
//
// R10 (from R9 504us: MFMA 21 / VALU 41 / conflicts 3.7e7 / occupancy 22% —
// latency-bound, no pipe saturated):
//  - activations in LDS as SEPARATE hi/lo bf16 planes, row stride 68 dwords
//    ([hi[64] | lo[64] | pad] ushorts): A-frag = 2 direct ds_read_b128, ZERO
//    v_perm + ZERO xor address math; stride 68 = 4 mod 32 staggers rows ->
//    even bank spread without any swizzle.
//  - 3 buffers only (XE aliases RS) x 17.4 KB = 52.2 KB -> 3 blocks/CU
//    (156.7 of 160 KB), occupancy 2 -> 3 waves/SIMD.
//  - x read directly per-lane from global (kills the x-staging barrier).

#define NB 1024
#define ROW 68          // dwords per activation row
#define ROWU 136        // ushorts per row

typedef float f32x4 __attribute__((ext_vector_type(4)));
typedef __bf16 bf16x8 __attribute__((ext_vector_type(8)));
typedef int i32x4 __attribute__((ext_vector_type(4)));
typedef unsigned int u32;
typedef unsigned short u16;

#define MFMA(a, b, c) __builtin_amdgcn_mfma_f32_16x16x32_bf16(a, b, c, 0, 0, 0)

__device__ __forceinline__ float fexp(float x) {
    return __builtin_amdgcn_exp2f(x * 1.44269504088896341f);
}
__device__ __forceinline__ float fsigmoid(float x) {
    return __builtin_amdgcn_rcpf(1.0f + fexp(-x));
}
__device__ __forceinline__ float ftanh(float x) {
    return 1.0f - 2.0f * __builtin_amdgcn_rcpf(1.0f + fexp(2.0f * x));
}

// truncation split fp32 -> hi/lo bf16 bit patterns (identical numerics to R8/R9)
__device__ __forceinline__ void sw_pack(float v, u16& h, u16& l) {
    u32 bits = __builtin_bit_cast(u32, v);
    h = (u16)(bits >> 16);
    float lo = v - __builtin_bit_cast(float, bits & 0xFFFF0000u);
    l = (u16)(__builtin_bit_cast(u32, lo) >> 16);
}
__device__ __forceinline__ float ubf(u16 u) {
    return __builtin_bit_cast(float, ((u32)u) << 16);
}

__device__ __forceinline__ bf16x8 ldfrag(const u16* p) {
    i32x4 t = *(const i32x4*)p;
    return __builtin_bit_cast(bf16x8, t);
}
__device__ __forceinline__ void split8(f32x4 a0, f32x4 a1, bf16x8& hi, bf16x8& lo) {
    #pragma unroll
    for (int i = 0; i < 4; i++) {
        __bf16 h0 = (__bf16)a0[i]; hi[i] = h0;     lo[i] = (__bf16)(a0[i] - (float)h0);
        __bf16 h1 = (__bf16)a1[i]; hi[4 + i] = h1; lo[4 + i] = (__bf16)(a1[i] - (float)h1);
    }
}

// A-frag from plane layout: 8 k-values starting at kk (multiple of 8), row m
__device__ __forceinline__ void lda_plane(const u32* __restrict__ src, int m, int kk,
                                          bf16x8& hi, bf16x8& lo) {
    const u32* p = src + m * ROW + (kk >> 1);
    i32x4 h = *(const i32x4*)p;
    i32x4 L = *(const i32x4*)(p + 32);
    hi = __builtin_bit_cast(bf16x8, h);
    lo = __builtin_bit_cast(bf16x8, L);
}

// ---------------- ws layout (dwords) ----------------
// 0      FR_G1 [wq][nt][ks][half][lane][8bf16] 16384 dw ; 16384 FR_G2
// 32768  FR_C1 [wq][ks][half][lane][8] 8192 dw ; 40960 FR_C2
// 49152  FR_XE Win2 ; 53248 FR_HD Wo1
// 57344  seB [nb(16)][w(4)][lane(64)][16] fp32 (b_in2 folded)  65536 dw
// 122880 teo [768][64] fp32

__device__ __forceinline__ void wsplit(float v, u16* dhi, u16* dlo) {
    __bf16 h = (__bf16)v;
    __bf16 l = (__bf16)(v - (float)h);
    *dhi = __builtin_bit_cast(u16, h);
    *dlo = __builtin_bit_cast(u16, l);
}

__global__ void prep_gates(const float* __restrict__ Wg1, const float* __restrict__ Wg2,
                           u16* __restrict__ fr) {
    int i = blockIdx.x * 256 + threadIdx.x;            // [0, 4096)
    if (i >= 4096) return;
    int layer = i >> 11, r = i & 2047;
    int w = r >> 9; r &= 511; int nt = r >> 8; r &= 255; int ks = r >> 6; int lane = r & 63;
    const float* Wg = layer ? Wg2 : Wg1;
    int n = lane & 15, q = lane >> 4;
    int col = nt ? (64 + w * 16 + n) : (w * 16 + n);
    u16* dst = fr + layer * 32768 + (((w * 2 + nt) * 4 + ks) * 2) * 512 + lane * 8;
    #pragma unroll
    for (int j = 0; j < 8; j++) {
        int k = ks * 32 + q * 8 + j;
        float v = Wg[k * 128 + col] + Wg[(k + 128) * 128 + col];
        wsplit(v, dst + j, dst + 512 + j);
    }
}

__global__ void prep_cand(const float* __restrict__ Wc1, const float* __restrict__ Wc2,
                          u16* __restrict__ fr) {
    int i = blockIdx.x * 256 + threadIdx.x;            // [0, 2048)
    if (i >= 2048) return;
    int layer = i >> 10, r = i & 1023;
    int w = r >> 8; r &= 255; int ks = r >> 6; int lane = r & 63;
    const float* Wc = layer ? Wc2 : Wc1;
    int n = lane & 15, q = lane >> 4;
    int col = w * 16 + n;
    u16* dst = fr + 65536 + layer * 16384 + ((w * 4 + ks) * 2) * 512 + lane * 8;
    #pragma unroll
    for (int j = 0; j < 8; j++) {
        int k = ks * 32 + q * 8 + j;
        float v = Wc[k * 64 + col] + Wc[(k + 128) * 64 + col];
        wsplit(v, dst + j, dst + 512 + j);
    }
}

__global__ void prep_small(const float* __restrict__ Win2, const float* __restrict__ Wo1,
                           u16* __restrict__ fr) {
    int i = blockIdx.x * 256 + threadIdx.x;            // [0, 1024)
    if (i >= 1024) return;
    int kind = i >> 9, r = i & 511;
    int w = r >> 7; r &= 127; int ks = r >> 6; int lane = r & 63;
    const float* W = kind ? Wo1 : Win2;
    int n = lane & 15, q = lane >> 4;
    int col = w * 16 + n;
    u16* dst = fr + 98304 + kind * 8192 + ((w * 2 + ks) * 2) * 512 + lane * 8;
    #pragma unroll
    for (int j = 0; j < 8; j++) {
        int k = ks * 32 + q * 8 + j;
        float v = W[k * 64 + col];
        wsplit(v, dst + j, dst + 512 + j);
    }
}

// se lane-ordered: n = nb*64 + mt*16 + q*4 + r, d = w*16+n16, l = q*16+n16
__global__ void prep_se(const float* __restrict__ SE, const float* __restrict__ W1,
                        const float* __restrict__ b1, const float* __restrict__ W2,
                        const float* __restrict__ b2, const float* __restrict__ bin2,
                        float* __restrict__ seB) {
    __shared__ float h[64];
    int n = blockIdx.x, d = threadIdx.x;
    float acc = b1[d];
    for (int k = 0; k < 64; k++) acc = fmaf(SE[n * 64 + k], W1[k * 64 + d], acc);
    h[d] = fmaxf(acc, 0.0f);
    __syncthreads();
    float acc2 = b2[d];
    for (int k = 0; k < 64; k++) acc2 = fmaf(h[k], W2[k * 64 + d], acc2);
    int nb = n >> 6, tok = n & 63;
    int mt = tok >> 4, q = (tok >> 2) & 3, r = tok & 3;
    int w = d >> 4, n16 = d & 15;
    seB[(((nb * 4 + w) * 64) + q * 16 + n16) * 16 + mt * 4 + r] = acc2 + bin2[d];
}

__global__ void prep_te(const int* __restrict__ TE, const float* __restrict__ W1,
                        const float* __restrict__ b1, const float* __restrict__ W2,
                        const float* __restrict__ b2, float* __restrict__ teo) {
    __shared__ float h[64];
    int bp = blockIdx.x;
    int b = bp / 12, p = bp - b * 12;
    int d = threadIdx.x;
    int dow = TE[(b * 24 + p) * 2 + 0];
    int tod = TE[(b * 24 + p) * 2 + 1];
    float v = W1[dow * 64 + d] + W1[(7 + tod) * 64 + d] + b1[d];
    h[d] = fmaxf(v, 0.0f);
    __syncthreads();
    float acc = b2[d];
    for (int k = 0; k < 64; k++) acc = fmaf(h[k], W2[k * 64 + d], acc);
    teo[bp * 64 + d] = acc;
}

// one GRU step. Wave owns cols [16w,16w+16). XIN may alias RS (barrier Ba guards).
__device__ __forceinline__ void gru_full(
    const u32* __restrict__ XIN, u32* __restrict__ S, u32* __restrict__ RS,
    const u16* __restrict__ frG, const u16* __restrict__ frC,
    float bgr, float bgu, float bcc, int l, int col) {
    const int n16 = l & 15, q = l >> 4;
    u16* Sus = (u16*)S;
    u16* RSus = (u16*)RS;
    f32x4 accR[4], accU[4], accC[4];
    #pragma unroll
    for (int mt = 0; mt < 4; mt++) {
        accR[mt] = (f32x4)0.0f; accU[mt] = (f32x4)0.0f; accC[mt] = (f32x4)0.0f;
    }
    // phase 1: ks 0..1 (XIN K-half): one A-frag feeds R+U+C
    #pragma unroll
    for (int ks = 0; ks < 2; ks++) {
        bf16x8 bhiR = ldfrag(frG + ((0 * 4 + ks) * 2 + 0) * 512 + l * 8);
        bf16x8 bloR = ldfrag(frG + ((0 * 4 + ks) * 2 + 1) * 512 + l * 8);
        bf16x8 bhiU = ldfrag(frG + ((1 * 4 + ks) * 2 + 0) * 512 + l * 8);
        bf16x8 bloU = ldfrag(frG + ((1 * 4 + ks) * 2 + 1) * 512 + l * 8);
        bf16x8 bhiC = ldfrag(frC + (ks * 2 + 0) * 512 + l * 8);
        bf16x8 bloC = ldfrag(frC + (ks * 2 + 1) * 512 + l * 8);
        const int kk = ks * 32 + q * 8;
        #pragma unroll
        for (int mt = 0; mt < 4; mt++) {
            bf16x8 ahi, alo;
            lda_plane(XIN, mt * 16 + n16, kk, ahi, alo);
            accR[mt] = MFMA(ahi, bhiR, accR[mt]);
            accR[mt] = MFMA(alo, bhiR, accR[mt]);
            accR[mt] = MFMA(ahi, bloR, accR[mt]);
            accU[mt] = MFMA(ahi, bhiU, accU[mt]);
            accU[mt] = MFMA(alo, bhiU, accU[mt]);
            accU[mt] = MFMA(ahi, bloU, accU[mt]);
            accC[mt] = MFMA(ahi, bhiC, accC[mt]);
            accC[mt] = MFMA(alo, bhiC, accC[mt]);
            accC[mt] = MFMA(ahi, bloC, accC[mt]);
        }
    }
    // phase 2: ks 2..3 (S K-half): gates only
    #pragma unroll
    for (int ks = 2; ks < 4; ks++) {
        bf16x8 bhiR = ldfrag(frG + ((0 * 4 + ks) * 2 + 0) * 512 + l * 8);
        bf16x8 bloR = ldfrag(frG + ((0 * 4 + ks) * 2 + 1) * 512 + l * 8);
        bf16x8 bhiU = ldfrag(frG + ((1 * 4 + ks) * 2 + 0) * 512 + l * 8);
        bf16x8 bloU = ldfrag(frG + ((1 * 4 + ks) * 2 + 1) * 512 + l * 8);
        const int kk = (ks - 2) * 32 + q * 8;
        #pragma unroll
        for (int mt = 0; mt < 4; mt++) {
            bf16x8 ahi, alo;
            lda_plane(S, mt * 16 + n16, kk, ahi, alo);
            accR[mt] = MFMA(ahi, bhiR, accR[mt]);
            accR[mt] = MFMA(alo, bhiR, accR[mt]);
            accR[mt] = MFMA(ahi, bloR, accR[mt]);
            accU[mt] = MFMA(ahi, bhiU, accU[mt]);
            accU[mt] = MFMA(alo, bhiU, accU[mt]);
            accU[mt] = MFMA(ahi, bloU, accU[mt]);
        }
    }
    __syncthreads();   // Ba: all XIN/S gate reads done (RS may alias XIN)
    // rs = sigmoid(r) * s
    #pragma unroll
    for (int mt = 0; mt < 4; mt++)
        #pragma unroll
        for (int r = 0; r < 4; r++) {
            int tok = mt * 16 + q * 4 + r;
            int a = tok * ROWU + col;
            float sold = ubf(Sus[a]) + ubf(Sus[a + 64]);
            u16 h, lo16;
            sw_pack(fsigmoid(accR[mt][r] + bgr) * sold, h, lo16);
            RSus[a] = h; RSus[a + 64] = lo16;
        }
    __syncthreads();   // Bb: rs visible
    // phase 3: cand ks 2..3 (RS K-half) + state update
    #pragma unroll
    for (int ks = 2; ks < 4; ks++) {
        bf16x8 bhi = ldfrag(frC + (ks * 2 + 0) * 512 + l * 8);
        bf16x8 blo = ldfrag(frC + (ks * 2 + 1) * 512 + l * 8);
        const int kk = (ks - 2) * 32 + q * 8;
        #pragma unroll
        for (int mt = 0; mt < 4; mt++) {
            bf16x8 ahi, alo;
            lda_plane(RS, mt * 16 + n16, kk, ahi, alo);
            accC[mt] = MFMA(ahi, bhi, accC[mt]);
            accC[mt] = MFMA(alo, bhi, accC[mt]);
            accC[mt] = MFMA(ahi, blo, accC[mt]);
        }
    }
    #pragma unroll
    for (int mt = 0; mt < 4; mt++)
        #pragma unroll
        for (int r = 0; r < 4; r++) {
            int tok = mt * 16 + q * 4 + r;
            int a = tok * ROWU + col;
            float sold = ubf(Sus[a]) + ubf(Sus[a + 64]);
            float u = fsigmoid(accU[mt][r] + bgu);
            float cnd = ftanh(accC[mt][r] + bcc);
            u16 h, lo16;
            sw_pack(u * sold + (1.0f - u) * cnd, h, lo16);
            Sus[a] = h; Sus[a + 64] = lo16;
        }
    __syncthreads();   // Bc: state visible; RS reads done
}

__global__ __launch_bounds__(256, 3) void gman_main(
    const float* __restrict__ X, const float* __restrict__ ws,
    const float* __restrict__ Win1, const float* __restrict__ bin1,
    const float* __restrict__ bg1, const float* __restrict__ bc1,
    const float* __restrict__ bg2, const float* __restrict__ bc2,
    const float* __restrict__ bo1, const float* __restrict__ Wo2,
    const float* __restrict__ bo2, float* __restrict__ out) {
    // 3 x [64 rows][68 dw] = 52224 B -> 3 blocks/CU
    __shared__ u32 XR[64 * ROW], S1b[64 * ROW], S2b[64 * ROW];

    const int tid = threadIdx.x;
    const int l = tid & 63;
    const int w = tid >> 6;
    const int uw = __builtin_amdgcn_readfirstlane(w);
    const int n16 = l & 15, q = l >> 4;
    const int col = uw * 16 + n16;
    const int b = blockIdx.x >> 4;
    const int nb = blockIdx.x & 15;
    const int n0 = nb << 6;

    const u16* frU = (const u16*)ws;
    const u16* frG1 = frU + uw * 8192;
    const u16* frG2 = frU + 32768 + uw * 8192;
    const u16* frC1 = frU + 65536 + uw * 4096;
    const u16* frC2 = frU + 81920 + uw * 4096;
    const u16* frX  = frU + 98304 + uw * 2048;
    const u16* frH  = frU + 106496 + uw * 2048;
    const float* seQ = ws + 57344 + (((nb * 4 + uw) * 64) + l) * 16;
    const float* teo = ws + 122880;

    #pragma unroll
    for (int i = 0; i < 17; i++) {
        S1b[tid + i * 256] = 0u; S2b[tid + i * 256] = 0u;
    }

    f32x4 se_v[4];
    #pragma unroll
    for (int mt = 0; mt < 4; mt++) se_v[mt] = *(const f32x4*)(seQ + mt * 4);
    const float bg1r = bg1[col], bg1u = bg1[64 + col], bc1c = bc1[col];
    const float bg2r = bg2[col], bg2u = bg2[64 + col], bc2c = bc2[col];
    u16* XRus = (u16*)XR;

    __syncthreads();   // state init visible

    #pragma unroll 1
    for (int p = 0; p < 12; p++) {
        // xe GEMM: A = h1 = relu(x*Win1+bin1) built in regs (x direct from global)
        const float* Xp = X + (b * 12 + p) * NB + n0;
        f32x4 accX[4];
        #pragma unroll
        for (int mt = 0; mt < 4; mt++) accX[mt] = (f32x4)0.0f;
        #pragma unroll
        for (int ks = 0; ks < 2; ks++) {
            const int k0 = ks * 32 + q * 8;
            f32x4 w1a = *(const f32x4*)(Win1 + k0), w1b = *(const f32x4*)(Win1 + k0 + 4);
            f32x4 b1a = *(const f32x4*)(bin1 + k0), b1b = *(const f32x4*)(bin1 + k0 + 4);
            bf16x8 bhi = ldfrag(frX + (ks * 2 + 0) * 512 + l * 8);
            bf16x8 blo = ldfrag(frX + (ks * 2 + 1) * 512 + l * 8);
            #pragma unroll
            for (int mt = 0; mt < 4; mt++) {
                const float xm = Xp[mt * 16 + n16];
                f32x4 h0, h1v;
                #pragma unroll
                for (int i = 0; i < 4; i++) {
                    h0[i]  = fmaxf(fmaf(xm, w1a[i], b1a[i]), 0.0f);
                    h1v[i] = fmaxf(fmaf(xm, w1b[i], b1b[i]), 0.0f);
                }
                bf16x8 ahi, alo; split8(h0, h1v, ahi, alo);
                accX[mt] = MFMA(ahi, bhi, accX[mt]);
                accX[mt] = MFMA(alo, bhi, accX[mt]);
                accX[mt] = MFMA(ahi, blo, accX[mt]);
            }
        }
        const float tev = teo[(b * 12 + p) * 64 + col];
        // write XE planes (XR free: previous p's rs2 reads ended at Bc)
        #pragma unroll
        for (int mt = 0; mt < 4; mt++)
            #pragma unroll
            for (int r = 0; r < 4; r++) {
                int tok = mt * 16 + q * 4 + r;
                int a = tok * ROWU + col;
                u16 h, lo16;
                sw_pack(accX[mt][r] + se_v[mt][r] + tev, h, lo16);
                XRus[a] = h; XRus[a + 64] = lo16;
            }
        __syncthreads();   // B1: XE complete

        gru_full(XR, S1b, XR, frG1, frC1, bg1r, bg1u, bc1c, l, col);
        gru_full(S1b, S2b, XR, frG2, frC2, bg2r, bg2u, bc2c, l, col);
    }

    // head: h = relu(S2@Wo1+bo1) via MFMA into XR planes, then y GEMV
    f32x4 accH[4];
    #pragma unroll
    for (int mt = 0; mt < 4; mt++) accH[mt] = (f32x4)0.0f;
    #pragma unroll
    for (int ks = 0; ks < 2; ks++) {
        bf16x8 bhi = ldfrag(frH + (ks * 2 + 0) * 512 + l * 8);
        bf16x8 blo = ldfrag(frH + (ks * 2 + 1) * 512 + l * 8);
        const int kk = ks * 32 + q * 8;
        #pragma unroll
        for (int mt = 0; mt < 4; mt++) {
            bf16x8 ahi, alo;
            lda_plane(S2b, mt * 16 + n16, kk, ahi, alo);
            accH[mt] = MFMA(ahi, bhi, accH[mt]);
            accH[mt] = MFMA(alo, bhi, accH[mt]);
            accH[mt] = MFMA(ahi, blo, accH[mt]);
        }
    }
    const float bo1c = bo1[col];
    #pragma unroll
    for (int mt = 0; mt < 4; mt++)
        #pragma unroll
        for (int r = 0; r < 4; r++) {
            int tok = mt * 16 + q * 4 + r;
            int a = tok * ROWU + col;
            u16 h, lo16;
            sw_pack(fmaxf(accH[mt][r] + bo1c, 0.0f), h, lo16);
            XRus[a] = h; XRus[a + 64] = lo16;
        }
    __syncthreads();
    // y: lane = token (row l), wave owns q-cols 3w..3w+2
    float y0 = bo2[3 * uw + 0], y1 = bo2[3 * uw + 1], y2 = bo2[3 * uw + 2];
    const u32* hrow = XR + l * ROW;
    #pragma unroll
    for (int i = 0; i < 32; i++) {
        u32 hd = hrow[i], ld = hrow[32 + i];
        float h0 = __builtin_bit_cast(float, hd << 16) + __builtin_bit_cast(float, ld << 16);
        float h1 = __builtin_bit_cast(float, hd & 0xFFFF0000u)
                 + __builtin_bit_cast(float, ld & 0xFFFF0000u);
        int j = 2 * i;
        y0 = fmaf(h0, Wo2[j * 12 + 3 * uw + 0], y0);
        y1 = fmaf(h0, Wo2[j * 12 + 3 * uw + 1], y1);
        y2 = fmaf(h0, Wo2[j * 12 + 3 * uw + 2], y2);
        y0 = fmaf(h1, Wo2[(j + 1) * 12 + 3 * uw + 0], y0);
        y1 = fmaf(h1, Wo2[(j + 1) * 12 + 3 * uw + 1], y1);
        y2 = fmaf(h1, Wo2[(j + 1) * 12 + 3 * uw + 2], y2);
    }
    out[(b * 12 + 3 * uw + 0) * NB + n0 + l] = y0;
    out[(b * 12 + 3 * uw + 1) * NB + n0 + l] = y1;
    out[(b * 12 + 3 * uw + 2) * NB + n0 + l] = y2;
}

extern "C" void kernel_launch(void* const* d_in, const int* in_sizes, int n_in,
                              void* d_out, int out_size, void* d_ws, size_t ws_size,
                              hipStream_t stream) {
    const float* X    = (const float*)d_in[0];
    // d_in[1]=ZC, d_in[2]=ZF unused by the reference
    const float* SE   = (const float*)d_in[3];
    const float* Wse1 = (const float*)d_in[4];
    const float* bse1 = (const float*)d_in[5];
    const float* Wse2 = (const float*)d_in[6];
    const float* bse2 = (const float*)d_in[7];
    const float* Wte1 = (const float*)d_in[8];
    const float* bte1 = (const float*)d_in[9];
    const float* Wte2 = (const float*)d_in[10];
    const float* bte2 = (const float*)d_in[11];
    const float* Win1 = (const float*)d_in[12];
    const float* bin1 = (const float*)d_in[13];
    const float* Win2 = (const float*)d_in[14];
    const float* bin2 = (const float*)d_in[15];
    const float* Wg1  = (const float*)d_in[16];
    const float* bg1  = (const float*)d_in[17];
    const float* Wc1  = (const float*)d_in[18];
    const float* bc1  = (const float*)d_in[19];
    const float* Wg2  = (const float*)d_in[20];
    const float* bg2  = (const float*)d_in[21];
    const float* Wc2  = (const float*)d_in[22];
    const float* bc2  = (const float*)d_in[23];
    const float* Wo1  = (const float*)d_in[24];
    const float* bo1  = (const float*)d_in[25];
    const float* Wo2  = (const float*)d_in[26];
    const float* bo2  = (const float*)d_in[27];
    const int*   TE   = (const int*)d_in[28];

    float* ws = (float*)d_ws;                  // 172032 floats = 688 KB
    u16* fr = (u16*)ws;
    float* seB = ws + 57344;
    float* teo = ws + 122880;
    float* out = (float*)d_out;

    prep_gates<<<16, 256, 0, stream>>>(Wg1, Wg2, fr);
    prep_cand<<<8, 256, 0, stream>>>(Wc1, Wc2, fr);
    prep_small<<<4, 256, 0, stream>>>(Win2, Wo1, fr);
    prep_se<<<1024, 64, 0, stream>>>(SE, Wse1, bse1, Wse2, bse2, bin2, seB);
    prep_te<<<768, 64, 0, stream>>>(TE, Wte1, bte1, Wte2, bte2, teo);
    gman_main<<<1024, 256, 0, stream>>>(X, ws, Win1, bin1, bg1, bc1, bg2, bc2,
                                        bo1, Wo2, bo2, out);
}

// Round 11
// 575.777 us; speedup vs baseline: 1.3866x; 1.3866x over previous
//
#include <hip/hip_runtime.h>

// GMAN pipeline, fully fused, MFMA edition. support = I -> per-block token GEMMs.
// B=64, P=Q=12, N=1024, D=64. Output [B,Q,N] fp32.
//
// R11 = R9 base (504us: 256 thr / 4 waves / 64 tokens / packed hi|lo dword
// activations / 64 KB LDS / 2 blocks/CU) with the fragment stream attacked:
//  - R7-R10 law: dur tracks the per-p-step weight-fragment global stream
//    (~52 KB/wave); L2 absorbs only ~70% of it and less at higher concurrency.
//  - gate frags (16/layer x 2 layers = 128 VGPRs) made TRULY resident via
//    asm volatile "+v" pins: an asm output cannot be rematerialized, so the
//    compiler cannot sink the loads back into the loop (R9's failure mode:
//    with no intervening stores, re-loading was legal and it chose that).
//    -> kills 32 KB of the 52 KB/wave/p-step stream + gate-phase vmcnt waits.
//  - sold cached in regs between rs and state update (saves 32 LDS reads+unpacks
//    per layer).
//  - WRITE_SIZE is the spill tripwire (flat ~138 MB = no spill).

#define NB 1024

typedef float f32x4 __attribute__((ext_vector_type(4)));
typedef __bf16 bf16x8 __attribute__((ext_vector_type(8)));
typedef int i32x4 __attribute__((ext_vector_type(4)));
typedef unsigned int u32;
typedef unsigned short u16;

#define MFMA(a, b, c) __builtin_amdgcn_mfma_f32_16x16x32_bf16(a, b, c, 0, 0, 0)

__device__ __forceinline__ float fexp(float x) {
    return __builtin_amdgcn_exp2f(x * 1.44269504088896341f);
}
__device__ __forceinline__ float fsigmoid(float x) {
    return __builtin_amdgcn_rcpf(1.0f + fexp(-x));
}
__device__ __forceinline__ float ftanh(float x) {
    return 1.0f - 2.0f * __builtin_amdgcn_rcpf(1.0f + fexp(2.0f * x));
}

// pack fp32 -> {bf16 hi | bf16 lo} in one dword (truncation split)
__device__ __forceinline__ u32 packf(float v) {
    u32 u = __builtin_bit_cast(u32, v);
    u32 hb = u & 0xFFFF0000u;
    float lo = v - __builtin_bit_cast(float, hb);
    return hb | (__builtin_bit_cast(u32, lo) >> 16);
}
__device__ __forceinline__ float unpackf(u32 u) {
    return __builtin_bit_cast(float, u & 0xFFFF0000u)
         + __builtin_bit_cast(float, u << 16);
}

__device__ __forceinline__ bf16x8 ldfrag(const u16* p) {
    i32x4 t = *(const i32x4*)p;
    return __builtin_bit_cast(bf16x8, t);
}
// pin a fragment's 4 VGPRs: asm output is non-rematerializable -> forced residency
__device__ __forceinline__ bf16x8 pin(bf16x8 v) {
    i32x4 t = __builtin_bit_cast(i32x4, v);
    asm volatile("" : "+v"(t));
    return __builtin_bit_cast(bf16x8, t);
}
__device__ __forceinline__ void split8(f32x4 a0, f32x4 a1, bf16x8& hi, bf16x8& lo) {
    #pragma unroll
    for (int i = 0; i < 4; i++) {
        __bf16 h0 = (__bf16)a0[i]; hi[i] = h0;     lo[i] = (__bf16)(a0[i] - (float)h0);
        __bf16 h1 = (__bf16)a1[i]; hi[4 + i] = h1; lo[4 + i] = (__bf16)(a1[i] - (float)h1);
    }
}

// swizzle: xor k bits 2..4 by t bits; k bits 0-1 intact -> 4-dword windows legal
#define SWZ(t) ((((t) & 3) << 3) ^ ((t) & 4) ^ (((t) & 8) << 1))
#define SW(t, k) ((t) * 64 + ((k) ^ SWZ(t)))

// read packed A-frag: 8 consecutive k from swizzled row m, extract hi/lo via v_perm
__device__ __forceinline__ void lda_packed(const u32* __restrict__ src, int m, int kk,
                                           bf16x8& hi, bf16x8& lo) {
    const int sk = kk ^ SWZ(m);
    i32x4 d0 = *(const i32x4*)(src + m * 64 + sk);
    i32x4 d1 = *(const i32x4*)(src + m * 64 + (sk ^ 4));
    i32x4 h, L;
    h[0] = (int)__builtin_amdgcn_perm((u32)d0[1], (u32)d0[0], 0x07060302u);
    h[1] = (int)__builtin_amdgcn_perm((u32)d0[3], (u32)d0[2], 0x07060302u);
    h[2] = (int)__builtin_amdgcn_perm((u32)d1[1], (u32)d1[0], 0x07060302u);
    h[3] = (int)__builtin_amdgcn_perm((u32)d1[3], (u32)d1[2], 0x07060302u);
    L[0] = (int)__builtin_amdgcn_perm((u32)d0[1], (u32)d0[0], 0x05040100u);
    L[1] = (int)__builtin_amdgcn_perm((u32)d0[3], (u32)d0[2], 0x05040100u);
    L[2] = (int)__builtin_amdgcn_perm((u32)d1[1], (u32)d1[0], 0x05040100u);
    L[3] = (int)__builtin_amdgcn_perm((u32)d1[3], (u32)d1[2], 0x05040100u);
    hi = __builtin_bit_cast(bf16x8, h);
    lo = __builtin_bit_cast(bf16x8, L);
}

// ---------------- ws layout (dwords) ----------------
// 0      FR_G1 [wq][nt][ks][half][lane][8bf16] 16384 dw ; 16384 FR_G2
// 32768  FR_C1 [wq][ks][half][lane][8] 8192 dw ; 40960 FR_C2
// 49152  FR_XE Win2 ; 53248 FR_HD Wo1
// 57344  seB [nb(16)][w(4)][lane(64)][16] fp32 (b_in2 folded)  65536 dw
// 122880 teo [768][64] fp32

__device__ __forceinline__ void wsplit(float v, u16* dhi, u16* dlo) {
    __bf16 h = (__bf16)v;
    __bf16 l = (__bf16)(v - (float)h);
    *dhi = __builtin_bit_cast(u16, h);
    *dlo = __builtin_bit_cast(u16, l);
}

__global__ void prep_gates(const float* __restrict__ Wg1, const float* __restrict__ Wg2,
                           u16* __restrict__ fr) {
    int i = blockIdx.x * 256 + threadIdx.x;            // [0, 4096)
    if (i >= 4096) return;
    int layer = i >> 11, r = i & 2047;
    int w = r >> 9; r &= 511; int nt = r >> 8; r &= 255; int ks = r >> 6; int lane = r & 63;
    const float* Wg = layer ? Wg2 : Wg1;
    int n = lane & 15, q = lane >> 4;
    int col = nt ? (64 + w * 16 + n) : (w * 16 + n);
    u16* dst = fr + layer * 32768 + (((w * 2 + nt) * 4 + ks) * 2) * 512 + lane * 8;
    #pragma unroll
    for (int j = 0; j < 8; j++) {
        int k = ks * 32 + q * 8 + j;
        float v = Wg[k * 128 + col] + Wg[(k + 128) * 128 + col];
        wsplit(v, dst + j, dst + 512 + j);
    }
}

__global__ void prep_cand(const float* __restrict__ Wc1, const float* __restrict__ Wc2,
                          u16* __restrict__ fr) {
    int i = blockIdx.x * 256 + threadIdx.x;            // [0, 2048)
    if (i >= 2048) return;
    int layer = i >> 10, r = i & 1023;
    int w = r >> 8; r &= 255; int ks = r >> 6; int lane = r & 63;
    const float* Wc = layer ? Wc2 : Wc1;
    int n = lane & 15, q = lane >> 4;
    int col = w * 16 + n;
    u16* dst = fr + 65536 + layer * 16384 + ((w * 4 + ks) * 2) * 512 + lane * 8;
    #pragma unroll
    for (int j = 0; j < 8; j++) {
        int k = ks * 32 + q * 8 + j;
        float v = Wc[k * 64 + col] + Wc[(k + 128) * 64 + col];
        wsplit(v, dst + j, dst + 512 + j);
    }
}

__global__ void prep_small(const float* __restrict__ Win2, const float* __restrict__ Wo1,
                           u16* __restrict__ fr) {
    int i = blockIdx.x * 256 + threadIdx.x;            // [0, 1024)
    if (i >= 1024) return;
    int kind = i >> 9, r = i & 511;
    int w = r >> 7; r &= 127; int ks = r >> 6; int lane = r & 63;
    const float* W = kind ? Wo1 : Win2;
    int n = lane & 15, q = lane >> 4;
    int col = w * 16 + n;
    u16* dst = fr + 98304 + kind * 8192 + ((w * 2 + ks) * 2) * 512 + lane * 8;
    #pragma unroll
    for (int j = 0; j < 8; j++) {
        int k = ks * 32 + q * 8 + j;
        float v = W[k * 64 + col];
        wsplit(v, dst + j, dst + 512 + j);
    }
}

// se lane-ordered: n = nb*64 + mt*16 + q*4 + r, d = w*16+n16, l = q*16+n16
__global__ void prep_se(const float* __restrict__ SE, const float* __restrict__ W1,
                        const float* __restrict__ b1, const float* __restrict__ W2,
                        const float* __restrict__ b2, const float* __restrict__ bin2,
                        float* __restrict__ seB) {
    __shared__ float h[64];
    int n = blockIdx.x, d = threadIdx.x;
    float acc = b1[d];
    for (int k = 0; k < 64; k++) acc = fmaf(SE[n * 64 + k], W1[k * 64 + d], acc);
    h[d] = fmaxf(acc, 0.0f);
    __syncthreads();
    float acc2 = b2[d];
    for (int k = 0; k < 64; k++) acc2 = fmaf(h[k], W2[k * 64 + d], acc2);
    int nb = n >> 6, tok = n & 63;
    int mt = tok >> 4, q = (tok >> 2) & 3, r = tok & 3;
    int w = d >> 4, n16 = d & 15;
    seB[(((nb * 4 + w) * 64) + q * 16 + n16) * 16 + mt * 4 + r] = acc2 + bin2[d];
}

__global__ void prep_te(const int* __restrict__ TE, const float* __restrict__ W1,
                        const float* __restrict__ b1, const float* __restrict__ W2,
                        const float* __restrict__ b2, float* __restrict__ teo) {
    __shared__ float h[64];
    int bp = blockIdx.x;
    int b = bp / 12, p = bp - b * 12;
    int d = threadIdx.x;
    int dow = TE[(b * 24 + p) * 2 + 0];
    int tod = TE[(b * 24 + p) * 2 + 1];
    float v = W1[dow * 64 + d] + W1[(7 + tod) * 64 + d] + b1[d];
    h[d] = fmaxf(v, 0.0f);
    __syncthreads();
    float acc = b2[d];
    for (int k = 0; k < 64; k++) acc = fmaf(h[k], W2[k * 64 + d], acc);
    teo[bp * 64 + d] = acc;
}

// full GRU step. Wave owns cols [16w,16w+16). g[16] VGPR-resident (pinned).
__device__ __forceinline__ void gru_full(
    const u32* __restrict__ XIN, u32* __restrict__ S, u32* __restrict__ RS,
    const bf16x8 (&g)[16], const u16* __restrict__ frC,
    float bgr, float bgu, float bcc, int l, int col) {
    const int n16 = l & 15, q = l >> 4;
    f32x4 accR[4], accU[4], accC[4];
    #pragma unroll
    for (int mt = 0; mt < 4; mt++) {
        accR[mt] = (f32x4)0.0f; accU[mt] = (f32x4)0.0f; accC[mt] = (f32x4)0.0f;
    }
    // phase 1: ks 0..1 (XIN K-half): one A-frag feeds R+U+C
    #pragma unroll
    for (int ks = 0; ks < 2; ks++) {
        bf16x8 bhiC = ldfrag(frC + (ks * 2 + 0) * 512 + l * 8);
        bf16x8 bloC = ldfrag(frC + (ks * 2 + 1) * 512 + l * 8);
        const int kk = ks * 32 + q * 8;
        #pragma unroll
        for (int mt = 0; mt < 4; mt++) {
            bf16x8 ahi, alo;
            lda_packed(XIN, mt * 16 + n16, kk, ahi, alo);
            accR[mt] = MFMA(ahi, g[ks * 2 + 0], accR[mt]);
            accR[mt] = MFMA(alo, g[ks * 2 + 0], accR[mt]);
            accR[mt] = MFMA(ahi, g[ks * 2 + 1], accR[mt]);
            accU[mt] = MFMA(ahi, g[8 + ks * 2 + 0], accU[mt]);
            accU[mt] = MFMA(alo, g[8 + ks * 2 + 0], accU[mt]);
            accU[mt] = MFMA(ahi, g[8 + ks * 2 + 1], accU[mt]);
            accC[mt] = MFMA(ahi, bhiC, accC[mt]);
            accC[mt] = MFMA(alo, bhiC, accC[mt]);
            accC[mt] = MFMA(ahi, bloC, accC[mt]);
        }
    }
    // phase 2: ks 2..3 (S K-half): gates only
    #pragma unroll
    for (int ks = 2; ks < 4; ks++) {
        const int kk = (ks - 2) * 32 + q * 8;
        #pragma unroll
        for (int mt = 0; mt < 4; mt++) {
            bf16x8 ahi, alo;
            lda_packed(S, mt * 16 + n16, kk, ahi, alo);
            accR[mt] = MFMA(ahi, g[ks * 2 + 0], accR[mt]);
            accR[mt] = MFMA(alo, g[ks * 2 + 0], accR[mt]);
            accR[mt] = MFMA(ahi, g[ks * 2 + 1], accR[mt]);
            accU[mt] = MFMA(ahi, g[8 + ks * 2 + 0], accU[mt]);
            accU[mt] = MFMA(alo, g[8 + ks * 2 + 0], accU[mt]);
            accU[mt] = MFMA(ahi, g[8 + ks * 2 + 1], accU[mt]);
        }
    }
    // rs = sigmoid(r) * s ; cache sold for the update phase
    float soldv[16];
    #pragma unroll
    for (int mt = 0; mt < 4; mt++)
        #pragma unroll
        for (int r = 0; r < 4; r++) {
            int tok = mt * 16 + q * 4 + r;
            int a = SW(tok, col);
            float sold = unpackf(S[a]);
            soldv[mt * 4 + r] = sold;
            RS[a] = packf(fsigmoid(accR[mt][r] + bgr) * sold);
        }
    __syncthreads();   // rs visible
    // cand ks 2..3 (RS K-half)
    #pragma unroll
    for (int ks = 2; ks < 4; ks++) {
        bf16x8 bhi = ldfrag(frC + (ks * 2 + 0) * 512 + l * 8);
        bf16x8 blo = ldfrag(frC + (ks * 2 + 1) * 512 + l * 8);
        const int kk = (ks - 2) * 32 + q * 8;
        #pragma unroll
        for (int mt = 0; mt < 4; mt++) {
            bf16x8 ahi, alo;
            lda_packed(RS, mt * 16 + n16, kk, ahi, alo);
            accC[mt] = MFMA(ahi, bhi, accC[mt]);
            accC[mt] = MFMA(alo, bhi, accC[mt]);
            accC[mt] = MFMA(ahi, blo, accC[mt]);
        }
    }
    // state update (sold from regs)
    #pragma unroll
    for (int mt = 0; mt < 4; mt++)
        #pragma unroll
        for (int r = 0; r < 4; r++) {
            int tok = mt * 16 + q * 4 + r;
            int a = SW(tok, col);
            float u = fsigmoid(accU[mt][r] + bgu);
            float cnd = ftanh(accC[mt][r] + bcc);
            S[a] = packf(u * soldv[mt * 4 + r] + (1.0f - u) * cnd);
        }
    __syncthreads();   // state visible; RS reads done
}

__global__ __launch_bounds__(256, 2) void gman_main(
    const float* __restrict__ X, const float* __restrict__ ws,
    const float* __restrict__ Win1, const float* __restrict__ bin1,
    const float* __restrict__ bg1, const float* __restrict__ bc1,
    const float* __restrict__ bg2, const float* __restrict__ bc2,
    const float* __restrict__ bo1, const float* __restrict__ Wo2,
    const float* __restrict__ bo2, float* __restrict__ out) {
    __shared__ u32 XE[4096], S1[4096], S2[4096], RS[4096];   // 64 KB

    const int tid = threadIdx.x;
    const int l = tid & 63;
    const int w = tid >> 6;
    const int uw = __builtin_amdgcn_readfirstlane(w);
    const int n16 = l & 15, q = l >> 4;
    const int col = uw * 16 + n16;
    const int b = blockIdx.x >> 4;
    const int nb = blockIdx.x & 15;
    const int n0 = nb << 6;

    const u16* frU = (const u16*)ws;
    const u16* frG1 = frU + uw * 8192;
    const u16* frG2 = frU + 32768 + uw * 8192;
    const u16* frC1 = frU + 65536 + uw * 4096;
    const u16* frC2 = frU + 81920 + uw * 4096;
    const u16* frX  = frU + 98304 + uw * 2048;
    const u16* frH  = frU + 106496 + uw * 2048;
    const float* seQ = ws + 57344 + (((nb * 4 + uw) * 64) + l) * 16;
    const float* teo = ws + 122880;

    #pragma unroll
    for (int i = 0; i < 16; i++) { S1[tid + i * 256] = 0u; S2[tid + i * 256] = 0u; }

    // resident gate fragments, PINNED (128 VGPRs the compiler cannot re-load)
    bf16x8 g1[16], g2[16];
    #pragma unroll
    for (int i = 0; i < 16; i++) g1[i] = pin(ldfrag(frG1 + i * 512 + l * 8));
    #pragma unroll
    for (int i = 0; i < 16; i++) g2[i] = pin(ldfrag(frG2 + i * 512 + l * 8));

    f32x4 se_v[4];
    #pragma unroll
    for (int mt = 0; mt < 4; mt++) se_v[mt] = *(const f32x4*)(seQ + mt * 4);
    const float bg1r = bg1[col], bg1u = bg1[64 + col], bc1c = bc1[col];
    const float bg2r = bg2[col], bg2u = bg2[64 + col], bc2c = bc2[col];

    #pragma unroll 1
    for (int p = 0; p < 12; p++) {
        // stage raw x into RS[0..63] (RS dead here; prev iter ended with barrier)
        if (tid < 64) RS[tid] = __builtin_bit_cast(u32, X[(b * 12 + p) * NB + n0 + tid]);
        __syncthreads();
        // xe GEMM: A = h1 = relu(x*Win1+bin1) built in regs, B = Win2 quarter
        f32x4 accX[4];
        #pragma unroll
        for (int mt = 0; mt < 4; mt++) accX[mt] = (f32x4)0.0f;
        #pragma unroll
        for (int ks = 0; ks < 2; ks++) {
            const int k0 = ks * 32 + q * 8;
            f32x4 w1a = *(const f32x4*)(Win1 + k0), w1b = *(const f32x4*)(Win1 + k0 + 4);
            f32x4 b1a = *(const f32x4*)(bin1 + k0), b1b = *(const f32x4*)(bin1 + k0 + 4);
            bf16x8 bhi = ldfrag(frX + (ks * 2 + 0) * 512 + l * 8);
            bf16x8 blo = ldfrag(frX + (ks * 2 + 1) * 512 + l * 8);
            #pragma unroll
            for (int mt = 0; mt < 4; mt++) {
                const float xm = __builtin_bit_cast(float, RS[mt * 16 + n16]);
                f32x4 h0, h1v;
                #pragma unroll
                for (int i = 0; i < 4; i++) {
                    h0[i]  = fmaxf(fmaf(xm, w1a[i], b1a[i]), 0.0f);
                    h1v[i] = fmaxf(fmaf(xm, w1b[i], b1b[i]), 0.0f);
                }
                bf16x8 ahi, alo; split8(h0, h1v, ahi, alo);
                accX[mt] = MFMA(ahi, bhi, accX[mt]);
                accX[mt] = MFMA(alo, bhi, accX[mt]);
                accX[mt] = MFMA(ahi, blo, accX[mt]);
            }
        }
        const float tev = teo[(b * 12 + p) * 64 + col];
        __syncthreads();   // raw-x reads done (RS reused for rs inside gru_full)
        #pragma unroll
        for (int mt = 0; mt < 4; mt++)
            #pragma unroll
            for (int r = 0; r < 4; r++) {
                int tok = mt * 16 + q * 4 + r;
                XE[SW(tok, col)] = packf(accX[mt][r] + se_v[mt][r] + tev);
            }
        __syncthreads();   // XE complete

        gru_full(XE, S1, RS, g1, frC1, bg1r, bg1u, bc1c, l, col);
        gru_full(S1, S2, RS, g2, frC2, bg2r, bg2u, bc2c, l, col);
    }

    // head: h = relu(S2@Wo1+bo1) via MFMA into XE (packed), then y GEMV
    f32x4 accH[4];
    #pragma unroll
    for (int mt = 0; mt < 4; mt++) accH[mt] = (f32x4)0.0f;
    #pragma unroll
    for (int ks = 0; ks < 2; ks++) {
        bf16x8 bhi = ldfrag(frH + (ks * 2 + 0) * 512 + l * 8);
        bf16x8 blo = ldfrag(frH + (ks * 2 + 1) * 512 + l * 8);
        const int kk = ks * 32 + q * 8;
        #pragma unroll
        for (int mt = 0; mt < 4; mt++) {
            bf16x8 ahi, alo;
            lda_packed(S2, mt * 16 + n16, kk, ahi, alo);
            accH[mt] = MFMA(ahi, bhi, accH[mt]);
            accH[mt] = MFMA(alo, bhi, accH[mt]);
            accH[mt] = MFMA(ahi, blo, accH[mt]);
        }
    }
    const float bo1c = bo1[col];
    #pragma unroll
    for (int mt = 0; mt < 4; mt++)
        #pragma unroll
        for (int r = 0; r < 4; r++) {
            int tok = mt * 16 + q * 4 + r;
            XE[SW(tok, col)] = packf(fmaxf(accH[mt][r] + bo1c, 0.0f));
        }
    __syncthreads();
    // y: lane = token, wave owns q-cols 3w..3w+2
    const int swzt = SWZ(l);
    float y0 = bo2[3 * uw + 0], y1 = bo2[3 * uw + 1], y2 = bo2[3 * uw + 2];
    #pragma unroll
    for (int c = 0; c < 16; c++) {
        i32x4 d = *(const i32x4*)(XE + l * 64 + c * 4);
        const int j0 = (c * 4) ^ swzt;
        #pragma unroll
        for (int e = 0; e < 4; e++) {
            float hj = unpackf((u32)d[e]);
            int j = j0 + e;
            y0 = fmaf(hj, Wo2[j * 12 + 3 * uw + 0], y0);
            y1 = fmaf(hj, Wo2[j * 12 + 3 * uw + 1], y1);
            y2 = fmaf(hj, Wo2[j * 12 + 3 * uw + 2], y2);
        }
    }
    out[(b * 12 + 3 * uw + 0) * NB + n0 + l] = y0;
    out[(b * 12 + 3 * uw + 1) * NB + n0 + l] = y1;
    out[(b * 12 + 3 * uw + 2) * NB + n0 + l] = y2;
}

extern "C" void kernel_launch(void* const* d_in, const int* in_sizes, int n_in,
                              void* d_out, int out_size, void* d_ws, size_t ws_size,
                              hipStream_t stream) {
    const float* X    = (const float*)d_in[0];
    // d_in[1]=ZC, d_in[2]=ZF unused by the reference
    const float* SE   = (const float*)d_in[3];
    const float* Wse1 = (const float*)d_in[4];
    const float* bse1 = (const float*)d_in[5];
    const float* Wse2 = (const float*)d_in[6];
    const float* bse2 = (const float*)d_in[7];
    const float* Wte1 = (const float*)d_in[8];
    const float* bte1 = (const float*)d_in[9];
    const float* Wte2 = (const float*)d_in[10];
    const float* bte2 = (const float*)d_in[11];
    const float* Win1 = (const float*)d_in[12];
    const float* bin1 = (const float*)d_in[13];
    const float* Win2 = (const float*)d_in[14];
    const float* bin2 = (const float*)d_in[15];
    const float* Wg1  = (const float*)d_in[16];
    const float* bg1  = (const float*)d_in[17];
    const float* Wc1  = (const float*)d_in[18];
    const float* bc1  = (const float*)d_in[19];
    const float* Wg2  = (const float*)d_in[20];
    const float* bg2  = (const float*)d_in[21];
    const float* Wc2  = (const float*)d_in[22];
    const float* bc2  = (const float*)d_in[23];
    const float* Wo1  = (const float*)d_in[24];
    const float* bo1  = (const float*)d_in[25];
    const float* Wo2  = (const float*)d_in[26];
    const float* bo2  = (const float*)d_in[27];
    const int*   TE   = (const int*)d_in[28];

    float* ws = (float*)d_ws;                  // 172032 floats = 688 KB
    u16* fr = (u16*)ws;
    float* seB = ws + 57344;
    float* teo = ws + 122880;
    float* out = (float*)d_out;

    prep_gates<<<16, 256, 0, stream>>>(Wg1, Wg2, fr);
    prep_cand<<<8, 256, 0, stream>>>(Wc1, Wc2, fr);
    prep_small<<<4, 256, 0, stream>>>(Win2, Wo1, fr);
    prep_se<<<1024, 64, 0, stream>>>(SE, Wse1, bse1, Wse2, bse2, bin2, seB);
    prep_te<<<768, 64, 0, stream>>>(TE, Wte1, bte1, Wte2, bte2, teo);
    gman_main<<<1024, 256, 0, stream>>>(X, ws, Win1, bin1, bg1, bc1, bg2, bc2,
                                        bo1, Wo2, bo2, out);
}